// Round 3
// baseline (201.204 us; speedup 1.0000x reference)
//
#include <hip/hip_runtime.h>
#include <math.h>

namespace {
constexpr int S = 7;
constexpr int B = 2;
constexpr int C = 20;
constexpr int PF = B * 5 + C;   // 30 floats per cell (predictions)
constexpr int TF = 5 + C;       // 25 floats per cell (targets)
constexpr float EPS = 1e-6f;
constexpr float LAMBDA_COORD = 5.0f;
constexpr float LAMBDA_NOOBJ = 0.5f;

constexpr int WT = 64;            // threads per block = 1 wave
constexpr int CC = 32;            // cells per chunk
constexpr int NBUF = 3;           // triple buffer per wave
constexpr int NBLK = 1792;        // 7 blocks/CU x 256 CU (LDS-limited)
constexpr int PB = CC * PF;       // 960 floats  = 3840 B pred per chunk
constexpr int TB = CC * TF;       // 800 floats  = 3200 B tgt per chunk
}

#define GLOBAL_AS __attribute__((address_space(1)))
#define LDS_AS    __attribute__((address_space(3)))

// Per-cell loss terms, accumulating into v0..v3.
__device__ __forceinline__ void cell_terms(const float* __restrict__ p,
                                           const float* __restrict__ t,
                                           int cell,
                                           float& v0, float& v1, float& v2, float& v3)
{
    const float c0 = p[4], c1 = p[9];
    v2 += c0 * c0 + c1 * c1;                          // noobj base term

    if (t[4] > 0.f) {                                 // ~6% of lanes
        const int j = cell % S;
        const int i = (cell / S) % S;
        const float invS = 1.0f / (float)S;

        const float2 p01 = *(const float2*)(p + 0);   // (x0, y0)
        const float2 p23 = *(const float2*)(p + 2);   // (w0, h0)
        const float2 p67 = *(const float2*)(p + 6);   // (y1, w1)
        const float gx = t[0], gy = t[1], gw = t[2], gh = t[3];

        const float gcx = ((float)j + gx) * invS;
        const float gcy = ((float)i + gy) * invS;
        const float gx1 = gcx - gw * 0.5f, gy1 = gcy - gh * 0.5f;
        const float gx2 = gcx + gw * 0.5f, gy2 = gcy + gh * 0.5f;
        const float garea = (gx2 - gx1) * (gy2 - gy1);

        const float bx[B]  = {p01.x, p[5]};
        const float by[B]  = {p01.y, p67.x};
        const float bw_[B] = {p23.x, p67.y};
        const float bh[B]  = {p23.y, p[8]};
        const float cf[B]  = {c0, c1};
        float iou[B];
        #pragma unroll
        for (int b = 0; b < B; ++b) {
            const float cx = ((float)j + bx[b]) * invS;
            const float cy = ((float)i + by[b]) * invS;
            const float x1 = cx - bw_[b] * 0.5f, y1 = cy - bh[b] * 0.5f;
            const float x2 = cx + bw_[b] * 0.5f, y2 = cy + bh[b] * 0.5f;
            const float ix1 = fmaxf(x1, gx1), iy1 = fmaxf(y1, gy1);
            const float ix2 = fminf(x2, gx2), iy2 = fminf(y2, gy2);
            const float inter = fmaxf(ix2 - ix1, 0.f) * fmaxf(iy2 - iy1, 0.f);
            const float parea = (x2 - x1) * (y2 - y1);
            iou[b] = inter / (parea + garea - inter + EPS);
        }
        const int best = (iou[1] > iou[0]) ? 1 : 0;   // first max wins
        const float rconf = cf[best], riou = iou[best];

        const float dx = bx[best] - gx, dy = by[best] - gy;
        const float swd = sqrtf(bw_[best] + EPS) - sqrtf(gw + EPS);
        const float shd = sqrtf(bh[best] + EPS) - sqrtf(gh + EPS);
        v0 += dx*dx + dy*dy + swd*swd + shd*shd;      // coord
        const float dc = rconf - riou;
        v1 += dc * dc;                                 // conf_obj
        v2 -= rconf * rconf;                           // responsible box excluded

        // class: lse*sum(g) - dot(g,l). Logits in [0,1) -> no max pass needed.
        float se = 0.f, dot = 0.f, sg = 0.f;
        #pragma unroll
        for (int c = 0; c < C; c += 2) {
            const float2 lc = *(const float2*)(p + 10 + c);
            const float g0 = t[5 + c], g1 = t[6 + c];
            se  += __expf(lc.x) + __expf(lc.y);
            dot += g0 * lc.x + g1 * lc.y;
            sg  += g0 + g1;
        }
        v3 += __logf(se) * sg - dot;                   // class
    }
}

// One wave per block. Private triple-buffered LDS chunks, continuous async
// global_load_lds stream with COUNTED vmcnt (never drains to 0 until the
// wave's last chunk). No barriers, no __syncthreads in the loop. Steady
// state keeps 2 chunks (16 loads, ~14 KB) in flight per wave at all times.
__global__ __launch_bounds__(WT) void k_main(const float* __restrict__ pred,
                                             const float* __restrict__ tgt,
                                             float* __restrict__ part,
                                             int n_cells)
{
    __shared__ float lp[NBUF][PB];   // 3 x 3840 B
    __shared__ float lt[NBUF][TB];   // 3 x 3200 B  (21120 B total)

    const int lane = threadIdx.x;    // 0..63
    const int bid = blockIdx.x;
    const int NC = n_cells / CC;     // 25088 full chunks for the bench shape
    const int o4 = lane * 4;         // float offset for 16 B/lane loads

    // chunks owned by this block (cyclic): bid, bid+NBLK, ...
    int m = 0;
    if (bid < NC) m = (NC - bid - 1) / NBLK + 1;

    float v0 = 0.f, v1 = 0.f, v2 = 0.f, v3 = 0.f;

    // 8 unmasked 16B/lane DMA loads per chunk. Fractional tails are covered
    // by OVERLAPPING re-reads (same data written twice to LDS) so every load
    // is full-wave and fully in-bounds:
    //   pred 960 fl: [0,256) [256,512) [512,768) [704,960)
    //   tgt  800 fl: [0,256) [256,512) [512,768) [544,800)
    auto stage = [&](int buf, int c) {
        const float* ps = pred + (size_t)c * PB;
        const float* ts = tgt + (size_t)c * TB;
        float* dp = &lp[buf][0];
        float* dt = &lt[buf][0];
        __builtin_amdgcn_global_load_lds((const GLOBAL_AS void*)(ps + o4),
                                         (LDS_AS void*)(dp + o4), 16, 0, 0);
        __builtin_amdgcn_global_load_lds((const GLOBAL_AS void*)(ps + 256 + o4),
                                         (LDS_AS void*)(dp + 256 + o4), 16, 0, 0);
        __builtin_amdgcn_global_load_lds((const GLOBAL_AS void*)(ps + 512 + o4),
                                         (LDS_AS void*)(dp + 512 + o4), 16, 0, 0);
        __builtin_amdgcn_global_load_lds((const GLOBAL_AS void*)(ps + 704 + o4),
                                         (LDS_AS void*)(dp + 704 + o4), 16, 0, 0);
        __builtin_amdgcn_global_load_lds((const GLOBAL_AS void*)(ts + o4),
                                         (LDS_AS void*)(dt + o4), 16, 0, 0);
        __builtin_amdgcn_global_load_lds((const GLOBAL_AS void*)(ts + 256 + o4),
                                         (LDS_AS void*)(dt + 256 + o4), 16, 0, 0);
        __builtin_amdgcn_global_load_lds((const GLOBAL_AS void*)(ts + 512 + o4),
                                         (LDS_AS void*)(dt + 512 + o4), 16, 0, 0);
        __builtin_amdgcn_global_load_lds((const GLOBAL_AS void*)(ts + 544 + o4),
                                         (LDS_AS void*)(dt + 544 + o4), 16, 0, 0);
    };

    if (m > 0) stage(0, bid);
    if (m > 1) stage(1, bid + NBLK);
    if (m > 2) stage(2, bid + 2 * NBLK);

    for (int k = 0; k < m; ++k) {
        // FIFO vmcnt: wait until chunk k's 8 loads done, keep the rest in flight.
        const int rem = m - 1 - k;
        if (rem >= 2)      asm volatile("s_waitcnt vmcnt(16)" ::: "memory");
        else if (rem == 1) asm volatile("s_waitcnt vmcnt(8)" ::: "memory");
        else               asm volatile("s_waitcnt vmcnt(0)" ::: "memory");

        const int buf = k % NBUF;
        const int c = bid + k * NBLK;
        if (lane < CC)
            cell_terms(&lp[buf][lane * PF], &lt[buf][lane * TF],
                       c * CC + lane, v0, v1, v2, v3);
        // ds_reads of this buffer complete before the refill DMA can land.
        asm volatile("s_waitcnt lgkmcnt(0)" ::: "memory");
        if (k + NBUF < m) stage(buf, bid + (k + NBUF) * NBLK);
    }

    // remainder cells (none for the bench shape): direct-global path
    const int remc = n_cells - NC * CC;
    if (remc > 0 && bid == 0 && lane < remc) {
        const int cell = NC * CC + lane;
        cell_terms(pred + (size_t)cell * PF, tgt + (size_t)cell * TF, cell,
                   v0, v1, v2, v3);
    }

    // ---- reduce: single-wave butterfly -> per-block partial slot ----
    float v[4] = {v0, v1, v2, v3};
    #pragma unroll
    for (int off = 32; off >= 1; off >>= 1) {
        v[0] += __shfl_down(v[0], off, 64);
        v[1] += __shfl_down(v[1], off, 64);
        v[2] += __shfl_down(v[2], off, 64);
        v[3] += __shfl_down(v[3], off, 64);
    }
    if (lane == 0) {
        part[bid * 4 + 0] = v[0];
        part[bid * 4 + 1] = v[1];
        part[bid * 4 + 2] = v[2];
        part[bid * 4 + 3] = v[3];
    }
}

// Single block: reduce nblk x 4 partials, write 5 outputs.
__global__ __launch_bounds__(256) void k_fin(const float* __restrict__ part,
                                             float* __restrict__ out,
                                             int nblk, float n) {
    const int tid = threadIdx.x;
    float a0 = 0.f, a1 = 0.f, a2 = 0.f, a3 = 0.f;
    for (int r = tid; r < nblk; r += 256) {
        const float4 q = *(const float4*)(part + r * 4);
        a0 += q.x; a1 += q.y; a2 += q.z; a3 += q.w;
    }
    float v[4] = {a0, a1, a2, a3};
    #pragma unroll
    for (int off = 32; off >= 1; off >>= 1) {
        v[0] += __shfl_down(v[0], off, 64);
        v[1] += __shfl_down(v[1], off, 64);
        v[2] += __shfl_down(v[2], off, 64);
        v[3] += __shfl_down(v[3], off, 64);
    }
    __shared__ float red[16];
    const int lane = tid & 63;
    const int wave = tid >> 6;
    if (lane == 0) {
        red[wave * 4 + 0] = v[0];
        red[wave * 4 + 1] = v[1];
        red[wave * 4 + 2] = v[2];
        red[wave * 4 + 3] = v[3];
    }
    __syncthreads();
    if (tid == 0) {
        const float coord  = red[0] + red[4] + red[8] + red[12];
        const float cobj   = red[1] + red[5] + red[9] + red[13];
        const float cnoobj = red[2] + red[6] + red[10] + red[14];
        const float ccls   = red[3] + red[7] + red[11] + red[15];
        const float inv = 1.0f / n;
        out[0] = coord * inv;
        out[1] = cobj * inv;
        out[2] = cnoobj * inv;
        out[3] = ccls * inv;
        out[4] = (LAMBDA_COORD * coord + cobj + LAMBDA_NOOBJ * cnoobj + ccls) * inv;
    }
}

extern "C" void kernel_launch(void* const* d_in, const int* in_sizes, int n_in,
                              void* d_out, int out_size, void* d_ws, size_t ws_size,
                              hipStream_t stream) {
    const float* pred = (const float*)d_in[0];
    const float* tgt  = (const float*)d_in[1];
    float* out  = (float*)d_out;
    float* part = (float*)d_ws;

    const int n_cells = in_sizes[0] / PF;          // 802816
    const float bs = (float)(n_cells / (S * S));   // 16384

    k_main<<<NBLK, WT, 0, stream>>>(pred, tgt, part, n_cells);
    k_fin<<<1, 256, 0, stream>>>(part, out, NBLK, bs);
}